// Round 2
// baseline (2369.426 us; speedup 1.0000x reference)
//
#include <hip/hip_runtime.h>
#include <hip/hip_bf16.h>

using short8  = __attribute__((ext_vector_type(8))) short;
using short4v = __attribute__((ext_vector_type(4))) short;
using fx4     = __attribute__((ext_vector_type(4))) float;

#define NB 8
#define CDIM 256
#define HH 128
#define NPIX 16384
#define NG_ELEMS 131072.0f

#define XS_STRIDE 66   // 64 pix + 2 pad floats: 264B rows, 2-lane/bank LDS reads (free)

__device__ __forceinline__ float bf2f(short s) {
    union { unsigned u; float f; } c; c.u = ((unsigned)(unsigned short)s) << 16; return c.f;
}
__device__ __forceinline__ short f2bf(float f) {
    union { float f; unsigned u; } c; c.f = f;
    unsigned u = c.u;
    u += 0x7FFFu + ((u >> 16) & 1u);
    return (short)(u >> 16);
}
// packed RTNE fp32x2 -> bf16x2 (v_cvt_pk_bf16_f32 on gfx950)
__device__ __forceinline__ short2 f2bf2(float a, float b) {
    __hip_bfloat162 h = __float22bfloat162_rn(make_float2(a, b));
    union { __hip_bfloat162 b; short2 s; } c; c.b = h; return c.s;
}

// ---------------- Kernel W: wq/wk fp32 -> bf16 in MFMA fragment order ----------------
// WB[t][kc(8)][ntile(16)][lane(64)][8el]; lane=(quad*16+lr): value W[ntile*16+lr][kc*32+quad*8+e]
__global__ __launch_bounds__(256) void kW(const float* __restrict__ wq,
                                          const float* __restrict__ wk,
                                          short* __restrict__ WB) {
    int kc = blockIdx.x;      // 0..7
    int t  = blockIdx.y;      // 0..1
    const float* W = t ? wk : wq;
    int tid = threadIdx.x;
    int ntile = tid >> 4, lr = tid & 15;
    int n = ntile * 16 + lr;
#pragma unroll
    for (int quad = 0; quad < 4; ++quad) {
        const float* p = W + (size_t)n * CDIM + kc * 32 + quad * 8;
        fx4 v0 = *(const fx4*)p;
        fx4 v1 = *(const fx4*)(p + 4);
        union { short8 v; short2 h[4]; } s;
        s.h[0] = f2bf2(v0[0], v0[1]);
        s.h[1] = f2bf2(v0[2], v0[3]);
        s.h[2] = f2bf2(v1[0], v1[1]);
        s.h[3] = f2bf2(v1[2], v1[3]);
        *(short8*)(WB + ((((size_t)t * 8 + kc) * 16 + ntile) * 64 + quad * 16 + lr) * 8) = s.v;
    }
}

// ---------------- Kernel G: LDS-staged streaming GEMM + group stats --------------------
// v3: whole 256ch x 64pix fp32 tile staged via global_load_lds (fire-and-forget, one
// barrier), padded stride for conflict-free ds_read2_b32; A=W frags (L2-hot), B=X from
// LDS; D-layout gives short4 stores in [pix][o].
__global__ __launch_bounds__(256, 2) void kG(const float* __restrict__ xlo,
                                             const float* __restrict__ xhi,
                                             const short* __restrict__ WB,
                                             short* __restrict__ qt,
                                             short* __restrict__ kt,
                                             float* __restrict__ stats) {
    __shared__ float Xs[256 * XS_STRIDE];      // 67.6 KB -> 2 blocks/CU

    int m0 = blockIdx.x * 64;                  // 64 pixels per block
    int zy = blockIdx.y;                       // 0..15
    int b = zy >> 1, t = zy & 1;
    const float* X = (t ? xhi : xlo) + (size_t)b * CDIM * NPIX;
    const short* WBt = WB + (size_t)t * 8 * 16 * 64 * 8;
    short* OUT = (t ? kt : qt) + (size_t)b * NPIX * CDIM;
    int tid = threadIdx.x;
    int w = tid >> 6, l = tid & 63, lr = l & 15, quad = l >> 4;

    // ---- stage: wave w DMAs channels [w*64, w*64+64) ; lane l -> pixel l -------------
    {
        int cbase = w * 64;
#pragma unroll
        for (int cc = 0; cc < 64; ++cc) {
            int c = cbase + cc;
            __builtin_amdgcn_global_load_lds(
                (const __attribute__((address_space(1))) void*)(X + (size_t)c * NPIX + m0 + l),
                (__attribute__((address_space(3))) void*)(&Xs[c * XS_STRIDE]),
                4, 0, 0);
        }
    }
    __syncthreads();

    fx4 acc[4][4];                             // [out-tile m][pix-tile nt]
#pragma unroll
    for (int m = 0; m < 4; ++m)
#pragma unroll
        for (int n = 0; n < 4; ++n) { acc[m][n][0]=0.f; acc[m][n][1]=0.f; acc[m][n][2]=0.f; acc[m][n][3]=0.f; }

    // ---- main loop: 8 kc steps, all data on-chip ------------------------------------
#pragma unroll
    for (int kc = 0; kc < 8; ++kc) {
        short8 af[4];
        const short* wb = WBt + (((size_t)kc * 16 + w * 4) * 64 + l) * 8;
#pragma unroll
        for (int m = 0; m < 4; ++m)
            af[m] = *(const short8*)(wb + (size_t)m * 64 * 8);

        const float* xq = &Xs[(kc * 32 + quad * 8) * XS_STRIDE + lr];
#pragma unroll
        for (int nt = 0; nt < 4; ++nt) {
            union { short8 v; short2 h[4]; } s;
#pragma unroll
            for (int j = 0; j < 4; ++j) {
                float a = xq[(2 * j    ) * XS_STRIDE + nt * 16];
                float bv = xq[(2 * j + 1) * XS_STRIDE + nt * 16];
                s.h[j] = f2bf2(a, bv);
            }
            short8 bf = s.v;
#pragma unroll
            for (int m = 0; m < 4; ++m)
                acc[m][nt] = __builtin_amdgcn_mfma_f32_16x16x32_bf16(af[m], bf, acc[m][nt], 0, 0, 0);
        }
    }

    // group stats: lane holds o = w*64 + m*16 + quad*4 + r at pixel nt*16+lr.
    {
        float s[4][4], ss[4][4];
#pragma unroll
        for (int m = 0; m < 4; ++m)
#pragma unroll
            for (int r = 0; r < 4; ++r) {
                float a0 = acc[m][0][r], a1 = acc[m][1][r], a2 = acc[m][2][r], a3 = acc[m][3][r];
                s[m][r]  = (a0 + a1) + (a2 + a3);
                ss[m][r] = (a0 * a0 + a1 * a1) + (a2 * a2 + a3 * a3);
            }
#pragma unroll
        for (int m = 0; m < 4; ++m)
#pragma unroll
            for (int r = 0; r < 4; ++r) {
                float sv = s[m][r], sq = ss[m][r];
                sv += __shfl_xor(sv, 1);  sq += __shfl_xor(sq, 1);
                sv += __shfl_xor(sv, 2);  sq += __shfl_xor(sq, 2);
                sv += __shfl_xor(sv, 4);  sq += __shfl_xor(sq, 4);
                sv += __shfl_xor(sv, 8);  sq += __shfl_xor(sq, 8);
                if (lr == 0) {
                    int o = w * 64 + m * 16 + quad * 4 + r;
                    int g = o >> 3;
                    float* st = stats + ((size_t)(t * NB + b) * 32 + g) * 2;
                    atomicAdd(st, sv);
                    atomicAdd(st + 1, sq);
                }
            }
    }

    // store bf16 [pix][o]: 8-byte short4 per (m,nt)
#pragma unroll
    for (int n = 0; n < 4; ++n) {
        int pix = m0 + n * 16 + lr;
        short* op = OUT + (size_t)pix * CDIM + w * 64 + quad * 4;
#pragma unroll
        for (int m = 0; m < 4; ++m) {
            short2 p0 = f2bf2(acc[m][n][0], acc[m][n][1]);
            short2 p1 = f2bf2(acc[m][n][2], acc[m][n][3]);
            short4v v; v[0] = p0.x; v[1] = p0.y; v[2] = p1.x; v[3] = p1.y;
            *(short4v*)(op + m * 16) = v;
        }
    }
}

// ---------------- Kernel S: stats -> per-(tensor,b,o) scale/shift ----------------------
__global__ __launch_bounds__(256) void kS(const float* __restrict__ stats,
                                          const float* __restrict__ gq,
                                          const float* __restrict__ bq,
                                          const float* __restrict__ gk,
                                          const float* __restrict__ bk,
                                          float* __restrict__ scale,
                                          float* __restrict__ shift) {
    int id = blockIdx.x * 256 + threadIdx.x;   // 0..4095
    int t = id >> 11, b = (id >> 8) & 7, o = id & 255;
    int g = o >> 3;
    const float* st = stats + ((size_t)(t * NB + b) * 32 + g) * 2;
    float mean = st[0] * (1.0f / NG_ELEMS);
    float var  = st[1] * (1.0f / NG_ELEMS) - mean * mean;
    float rstd = rsqrtf(var + 1e-5f);
    float gamma = (t ? gk : gq)[o];
    float beta  = (t ? bk : bq)[o];
    float sc = gamma * rstd;
    scale[id] = sc;
    shift[id] = beta - mean * sc;
}

// ---------------- Kernel A: windowed attention + fp32 residual/output ------------------
__global__ __launch_bounds__(256) void kA(const short* __restrict__ qt,
                                          const short* __restrict__ kt,
                                          const float* __restrict__ scale,
                                          const float* __restrict__ shift,
                                          const float* __restrict__ xlo,
                                          float* __restrict__ outp) {
    __shared__ short Ks[64 * 264];     // normalized K window [j][c], pad 8
    __shared__ float SsF[64 * 68];     // scores fp32; later reused as Os (short, stride 136)
    __shared__ short Ps[64 * 72];      // softmax probs bf16 [i][j], pad 8
    short* Os = (short*)SsF;

    int blk = blockIdx.x;              // 0..2047
    int b = blk >> 8, wh = (blk >> 4) & 15, ww = blk & 15;
    int tid = threadIdx.x;
    int w = tid >> 6, l = tid & 63, lr = l & 15, quad = l >> 4;

    const float* sq = scale + (size_t)b * CDIM;
    const float* zq = shift + (size_t)b * CDIM;
    const float* sk = scale + (size_t)(NB + b) * CDIM;
    const float* zk = shift + (size_t)(NB + b) * CDIM;

    // build normalized K window in LDS
    {
        int oct = tid & 31;
        int j00 = tid >> 5;
        float skv[8], zkv[8];
#pragma unroll
        for (int e = 0; e < 8; ++e) { skv[e] = sk[oct * 8 + e]; zkv[e] = zk[oct * 8 + e]; }
#pragma unroll
        for (int it = 0; it < 8; ++it) {
            int j = j00 + it * 8;
            int pix = (wh * 8 + (j >> 3)) * HH + ww * 8 + (j & 7);
            short8 kv = *(const short8*)(kt + ((size_t)b * NPIX + pix) * CDIM + oct * 8);
            short8 nv;
#pragma unroll
            for (int e = 0; e < 8; ++e) nv[e] = f2bf(bf2f(kv[e]) * skv[e] + zkv[e]);
            *(short8*)(&Ks[j * 264 + oct * 8]) = nv;
        }
    }
    __syncthreads();

    // S = Qn @ Kn^T / 16 ; wave w computes rows [16w,16w+16)
    {
        fx4 accS[4];
#pragma unroll
        for (int nt = 0; nt < 4; ++nt) { accS[nt][0]=0.f; accS[nt][1]=0.f; accS[nt][2]=0.f; accS[nt][3]=0.f; }
        int qi = 16 * w + lr;
        int pixq = (wh * 8 + (qi >> 3)) * HH + ww * 8 + (qi & 7);
        const short* qrow = qt + ((size_t)b * NPIX + pixq) * CDIM;
#pragma unroll
        for (int kc = 0; kc < 8; ++kc) {
            int c0 = kc * 32 + quad * 8;
            short8 qv = *(const short8*)(qrow + c0);
            short8 aq;
#pragma unroll
            for (int e = 0; e < 8; ++e) aq[e] = f2bf(bf2f(qv[e]) * sq[c0 + e] + zq[c0 + e]);
#pragma unroll
            for (int nt = 0; nt < 4; ++nt) {
                short8 bk8 = *(const short8*)(&Ks[(nt * 16 + lr) * 264 + c0]);
                accS[nt] = __builtin_amdgcn_mfma_f32_16x16x32_bf16(aq, bk8, accS[nt], 0, 0, 0);
            }
        }
#pragma unroll
        for (int nt = 0; nt < 4; ++nt)
#pragma unroll
            for (int r = 0; r < 4; ++r)
                SsF[(16 * w + quad * 4 + r) * 68 + nt * 16 + lr] = accS[nt][r] * 0.0625f;
    }
    __syncthreads();

    // softmax over rows (4 threads per row)
    {
        int row = tid >> 2, seg = tid & 3;
        float v[16];
#pragma unroll
        for (int k4 = 0; k4 < 4; ++k4) {
            fx4 t4 = *(const fx4*)(&SsF[row * 68 + seg * 16 + k4 * 4]);
            v[k4*4+0] = t4[0]; v[k4*4+1] = t4[1]; v[k4*4+2] = t4[2]; v[k4*4+3] = t4[3];
        }
        float m = v[0];
#pragma unroll
        for (int e = 1; e < 16; ++e) m = fmaxf(m, v[e]);
        m = fmaxf(m, __shfl_xor(m, 1));
        m = fmaxf(m, __shfl_xor(m, 2));
        float s = 0.f;
#pragma unroll
        for (int e = 0; e < 16; ++e) { v[e] = __expf(v[e] - m); s += v[e]; }
        s += __shfl_xor(s, 1);
        s += __shfl_xor(s, 2);
        float inv = 1.0f / s;
        short8 p0, p1;
#pragma unroll
        for (int e = 0; e < 8; ++e) { p0[e] = f2bf(v[e] * inv); p1[e] = f2bf(v[8 + e] * inv); }
        *(short8*)(&Ps[row * 72 + seg * 16]) = p0;
        *(short8*)(&Ps[row * 72 + seg * 16 + 8]) = p1;
    }
    __syncthreads();

    // O = P @ Kn ; wave w computes channels [64w, 64w+64)
    fx4 accO[4][4];
#pragma unroll
    for (int mt = 0; mt < 4; ++mt)
#pragma unroll
        for (int nt = 0; nt < 4; ++nt) { accO[mt][nt][0]=0.f; accO[mt][nt][1]=0.f; accO[mt][nt][2]=0.f; accO[mt][nt][3]=0.f; }
#pragma unroll
    for (int kc2 = 0; kc2 < 2; ++kc2) {
        int j0 = kc2 * 32 + quad * 8;
        short8 ap[4];
#pragma unroll
        for (int mt = 0; mt < 4; ++mt)
            ap[mt] = *(const short8*)(&Ps[(mt * 16 + lr) * 72 + j0]);
#pragma unroll
        for (int nt = 0; nt < 4; ++nt) {
            int c = 64 * w + nt * 16 + lr;
            short8 bk8;
#pragma unroll
            for (int jj = 0; jj < 8; ++jj) bk8[jj] = Ks[(j0 + jj) * 264 + c];
#pragma unroll
            for (int mt = 0; mt < 4; ++mt)
                accO[mt][nt] = __builtin_amdgcn_mfma_f32_16x16x32_bf16(ap[mt], bk8, accO[mt][nt], 0, 0, 0);
        }
    }

    // epilogue in two halves (Os overlays Ss region), transposed, fp32 residual + store
    int half = w >> 1;
#pragma unroll
    for (int h2 = 0; h2 < 2; ++h2) {
        __syncthreads();
        if (half == h2) {
#pragma unroll
            for (int mt = 0; mt < 4; ++mt)
#pragma unroll
                for (int nt = 0; nt < 4; ++nt) {
                    int i = mt * 16 + quad * 4;
                    int cl = 64 * w + nt * 16 + lr - 128 * h2;   // 0..127
#pragma unroll
                    for (int r = 0; r < 4; ++r)
                        Os[(i + r) * 136 + cl] = f2bf(accO[mt][nt][r]);
                }
        }
        __syncthreads();
#pragma unroll
        for (int it = 0; it < 4; ++it) {
            int id = tid + it * 256;
            int cl = id & 127, h = id >> 7;   // h 0..7
            int cg = cl + 128 * h2;
            size_t gidx = ((size_t)(b * CDIM + cg)) * NPIX + (size_t)(wh * 8 + h) * HH + ww * 8;
            fx4 x0 = *(const fx4*)(xlo + gidx);
            fx4 x1 = *(const fx4*)(xlo + gidx + 4);
            fx4 r0, r1;
#pragma unroll
            for (int jj = 0; jj < 4; ++jj) {
                r0[jj] = bf2f(Os[(h * 8 + jj)     * 136 + cl]) + x0[jj];
                r1[jj] = bf2f(Os[(h * 8 + 4 + jj) * 136 + cl]) + x1[jj];
            }
            *(fx4*)(outp + gidx)     = r0;
            *(fx4*)(outp + gidx + 4) = r1;
        }
    }
}

extern "C" void kernel_launch(void* const* d_in, const int* in_sizes, int n_in,
                              void* d_out, int out_size, void* d_ws, size_t ws_size,
                              hipStream_t stream) {
    const float* xlo = (const float*)d_in[0];
    const float* xhi = (const float*)d_in[1];
    const float* wqp = (const float*)d_in[2];
    const float* wkp = (const float*)d_in[3];
    const float* gq  = (const float*)d_in[4];
    const float* bq  = (const float*)d_in[5];
    const float* gk  = (const float*)d_in[6];
    const float* bk  = (const float*)d_in[7];
    float* outp = (float*)d_out;
    char* ws = (char*)d_ws;
    size_t SZB = (size_t)NB * NPIX * CDIM * 2;   // 64 MB per bf16 tensor
    short* qt    = (short*)(ws);
    short* kt    = (short*)(ws + SZB);
    float* stats = (float*)(ws + 2 * SZB);
    float* scale = (float*)(ws + 2 * SZB + 4096);
    float* shift = (float*)(ws + 2 * SZB + 4096 + 16384);
    short* WB    = (short*)(ws + 2 * SZB + 4096 + 32768);

    hipMemsetAsync(stats, 0, 4096, stream);
    kW<<<dim3(8, 2), dim3(256), 0, stream>>>(wqp, wkp, WB);
    kG<<<dim3(256, 16), dim3(256), 0, stream>>>(xlo, xhi, WB, qt, kt, stats);
    kS<<<dim3(16), dim3(256), 0, stream>>>(stats, gq, bq, gk, bk, scale, shift);
    kA<<<dim3(2048), dim3(256), 0, stream>>>(qt, kt, scale, shift, xlo, outp);
}

// Round 3
// 560.091 us; speedup vs baseline: 4.2304x; 4.2304x over previous
//
#include <hip/hip_runtime.h>
#include <hip/hip_bf16.h>

using short8  = __attribute__((ext_vector_type(8))) short;
using short4v = __attribute__((ext_vector_type(4))) short;
using fx4     = __attribute__((ext_vector_type(4))) float;
using fx2     = __attribute__((ext_vector_type(2))) float;

#define NB 8
#define CDIM 256
#define HH 128
#define NPIX 16384
#define NG_ELEMS 131072.0f

#define XS_STRIDE 66   // 64 pix + 2 pad floats: 264B rows, 2-lane/bank LDS reads (free)

__device__ __forceinline__ float bf2f(short s) {
    union { unsigned u; float f; } c; c.u = ((unsigned)(unsigned short)s) << 16; return c.f;
}
__device__ __forceinline__ short f2bf(float f) {
    union { float f; unsigned u; } c; c.f = f;
    unsigned u = c.u;
    u += 0x7FFFu + ((u >> 16) & 1u);
    return (short)(u >> 16);
}
// packed RTNE fp32x2 -> bf16x2 (v_cvt_pk_bf16_f32 on gfx950)
__device__ __forceinline__ short2 f2bf2(float a, float b) {
    __hip_bfloat162 h = __float22bfloat162_rn(make_float2(a, b));
    union { __hip_bfloat162 b; short2 s; } c; c.b = h; return c.s;
}

// ---------------- Kernel W: wq/wk fp32 -> bf16 in MFMA fragment order ----------------
// WB[t][kc(8)][ntile(16)][lane(64)][8el]; lane=(quad*16+lr): value W[ntile*16+lr][kc*32+quad*8+e]
__global__ __launch_bounds__(256) void kW(const float* __restrict__ wq,
                                          const float* __restrict__ wk,
                                          short* __restrict__ WB) {
    int kc = blockIdx.x;      // 0..7
    int t  = blockIdx.y;      // 0..1
    const float* W = t ? wk : wq;
    int tid = threadIdx.x;
    int ntile = tid >> 4, lr = tid & 15;
    int n = ntile * 16 + lr;
#pragma unroll
    for (int quad = 0; quad < 4; ++quad) {
        const float* p = W + (size_t)n * CDIM + kc * 32 + quad * 8;
        fx4 v0 = *(const fx4*)p;
        fx4 v1 = *(const fx4*)(p + 4);
        union { short8 v; short2 h[4]; } s;
        s.h[0] = f2bf2(v0[0], v0[1]);
        s.h[1] = f2bf2(v0[2], v0[3]);
        s.h[2] = f2bf2(v1[0], v1[1]);
        s.h[3] = f2bf2(v1[2], v1[3]);
        *(short8*)(WB + ((((size_t)t * 8 + kc) * 16 + ntile) * 64 + quad * 16 + lr) * 8) = s.v;
    }
}

// ---------------- Kernel G: LDS-staged streaming GEMM + group partials -----------------
// v4: as v3 (global_load_lds staging, one barrier, A=W frags, B=X from LDS) but group
// stats go to per-block NON-ATOMIC partials (was: 2.1M contended atomicAdds = the wall).
__global__ __launch_bounds__(256, 2) void kG(const float* __restrict__ xlo,
                                             const float* __restrict__ xhi,
                                             const short* __restrict__ WB,
                                             short* __restrict__ qt,
                                             short* __restrict__ kt,
                                             fx2* __restrict__ partials) {
    __shared__ float Xs[256 * XS_STRIDE];      // 67.6 KB -> 2 blocks/CU

    int m0 = blockIdx.x * 64;                  // 64 pixels per block
    int zy = blockIdx.y;                       // 0..15
    int b = zy >> 1, t = zy & 1;
    const float* X = (t ? xhi : xlo) + (size_t)b * CDIM * NPIX;
    const short* WBt = WB + (size_t)t * 8 * 16 * 64 * 8;
    short* OUT = (t ? kt : qt) + (size_t)b * NPIX * CDIM;
    int tid = threadIdx.x;
    int w = tid >> 6, l = tid & 63, lr = l & 15, quad = l >> 4;

    // ---- stage: wave w DMAs channels [w*64, w*64+64) ; lane l -> pixel l -------------
    {
        int cbase = w * 64;
#pragma unroll
        for (int cc = 0; cc < 64; ++cc) {
            int c = cbase + cc;
            __builtin_amdgcn_global_load_lds(
                (const __attribute__((address_space(1))) void*)(X + (size_t)c * NPIX + m0 + l),
                (__attribute__((address_space(3))) void*)(&Xs[c * XS_STRIDE]),
                4, 0, 0);
        }
    }
    __syncthreads();

    fx4 acc[4][4];                             // [out-tile m][pix-tile nt]
#pragma unroll
    for (int m = 0; m < 4; ++m)
#pragma unroll
        for (int n = 0; n < 4; ++n) { acc[m][n][0]=0.f; acc[m][n][1]=0.f; acc[m][n][2]=0.f; acc[m][n][3]=0.f; }

    // ---- main loop: 8 kc steps, all data on-chip ------------------------------------
#pragma unroll
    for (int kc = 0; kc < 8; ++kc) {
        short8 af[4];
        const short* wb = WBt + (((size_t)kc * 16 + w * 4) * 64 + l) * 8;
#pragma unroll
        for (int m = 0; m < 4; ++m)
            af[m] = *(const short8*)(wb + (size_t)m * 64 * 8);

        const float* xq = &Xs[(kc * 32 + quad * 8) * XS_STRIDE + lr];
#pragma unroll
        for (int nt = 0; nt < 4; ++nt) {
            union { short8 v; short2 h[4]; } s;
#pragma unroll
            for (int j = 0; j < 4; ++j) {
                float a = xq[(2 * j    ) * XS_STRIDE + nt * 16];
                float bv = xq[(2 * j + 1) * XS_STRIDE + nt * 16];
                s.h[j] = f2bf2(a, bv);
            }
            short8 bf = s.v;
#pragma unroll
            for (int m = 0; m < 4; ++m)
                acc[m][nt] = __builtin_amdgcn_mfma_f32_16x16x32_bf16(af[m], bf, acc[m][nt], 0, 0, 0);
        }
    }

    // ---- group partials: lane owns o = w*64 + m*16 + quad*4 + r at pixel nt*16+lr ----
    // lr-butterfly over pixels, quad-pair combine (xor16), in-lane sum over r ->
    // lane 0 holds group w*8+m*2+0 ; lane 32 holds group w*8+m*2+1. No atomics.
    {
        float gs[4], gss[4];
#pragma unroll
        for (int m = 0; m < 4; ++m) {
            gs[m] = 0.f; gss[m] = 0.f;
#pragma unroll
            for (int r = 0; r < 4; ++r) {
                float a0 = acc[m][0][r], a1 = acc[m][1][r], a2 = acc[m][2][r], a3 = acc[m][3][r];
                float sv = (a0 + a1) + (a2 + a3);
                float sq = (a0 * a0 + a1 * a1) + (a2 * a2 + a3 * a3);
                sv += __shfl_xor(sv, 1);  sq += __shfl_xor(sq, 1);
                sv += __shfl_xor(sv, 2);  sq += __shfl_xor(sq, 2);
                sv += __shfl_xor(sv, 4);  sq += __shfl_xor(sq, 4);
                sv += __shfl_xor(sv, 8);  sq += __shfl_xor(sq, 8);
                sv += __shfl_xor(sv, 16); sq += __shfl_xor(sq, 16);   // quad-pair combine
                gs[m] += sv; gss[m] += sq;
            }
        }
        if (l == 0 || l == 32) {
            int h = l >> 5;
            fx2* pp = partials + ((size_t)zy * 256 + blockIdx.x) * 32 + w * 8 + h;
#pragma unroll
            for (int m = 0; m < 4; ++m) {
                fx2 v; v[0] = gs[m]; v[1] = gss[m];
                pp[m * 2] = v;
            }
        }
    }

    // store bf16 [pix][o]: 8-byte short4 per (m,nt)
#pragma unroll
    for (int n = 0; n < 4; ++n) {
        int pix = m0 + n * 16 + lr;
        short* op = OUT + (size_t)pix * CDIM + w * 64 + quad * 4;
#pragma unroll
        for (int m = 0; m < 4; ++m) {
            short2 p0 = f2bf2(acc[m][n][0], acc[m][n][1]);
            short2 p1 = f2bf2(acc[m][n][2], acc[m][n][3]);
            short4v v; v[0] = p0.x; v[1] = p0.y; v[2] = p1.x; v[3] = p1.y;
            *(short4v*)(op + m * 16) = v;
        }
    }
}

// ---------------- Kernel R: reduce per-block partials -> stats -------------------------
// one block per zy=(t,b): 256 threads; thread (j=tid>>5, slot=tid&31) sums 32 blocks.
__global__ __launch_bounds__(256) void kR(const fx2* __restrict__ partials,
                                          float* __restrict__ stats) {
    __shared__ fx2 red[8][32];
    int zy = blockIdx.x;                 // 0..15
    int b = zy >> 1, t = zy & 1;
    int tid = threadIdx.x;
    int j = tid >> 5, slot = tid & 31;
    fx2 acc; acc[0] = 0.f; acc[1] = 0.f;
#pragma unroll
    for (int i = 0; i < 32; ++i) {
        fx2 v = partials[((size_t)zy * 256 + j * 32 + i) * 32 + slot];
        acc[0] += v[0]; acc[1] += v[1];
    }
    red[j][slot] = acc;
    __syncthreads();
    if (tid < 32) {
        fx2 s = red[0][tid];
#pragma unroll
        for (int jj = 1; jj < 8; ++jj) { s[0] += red[jj][tid][0]; s[1] += red[jj][tid][1]; }
        float* st = stats + ((size_t)(t * NB + b) * 32 + tid) * 2;
        st[0] = s[0];
        st[1] = s[1];
    }
}

// ---------------- Kernel S: stats -> per-(tensor,b,o) scale/shift ----------------------
__global__ __launch_bounds__(256) void kS(const float* __restrict__ stats,
                                          const float* __restrict__ gq,
                                          const float* __restrict__ bq,
                                          const float* __restrict__ gk,
                                          const float* __restrict__ bk,
                                          float* __restrict__ scale,
                                          float* __restrict__ shift) {
    int id = blockIdx.x * 256 + threadIdx.x;   // 0..4095
    int t = id >> 11, b = (id >> 8) & 7, o = id & 255;
    int g = o >> 3;
    const float* st = stats + ((size_t)(t * NB + b) * 32 + g) * 2;
    float mean = st[0] * (1.0f / NG_ELEMS);
    float var  = st[1] * (1.0f / NG_ELEMS) - mean * mean;
    float rstd = rsqrtf(var + 1e-5f);
    float gamma = (t ? gk : gq)[o];
    float beta  = (t ? bk : bq)[o];
    float sc = gamma * rstd;
    scale[id] = sc;
    shift[id] = beta - mean * sc;
}

// ---------------- Kernel A: windowed attention + fp32 residual/output ------------------
__global__ __launch_bounds__(256) void kA(const short* __restrict__ qt,
                                          const short* __restrict__ kt,
                                          const float* __restrict__ scale,
                                          const float* __restrict__ shift,
                                          const float* __restrict__ xlo,
                                          float* __restrict__ outp) {
    __shared__ short Ks[64 * 264];     // normalized K window [j][c], pad 8
    __shared__ float SsF[64 * 68];     // scores fp32; later reused as Os (short, stride 136)
    __shared__ short Ps[64 * 72];      // softmax probs bf16 [i][j], pad 8
    short* Os = (short*)SsF;

    int blk = blockIdx.x;              // 0..2047
    int b = blk >> 8, wh = (blk >> 4) & 15, ww = blk & 15;
    int tid = threadIdx.x;
    int w = tid >> 6, l = tid & 63, lr = l & 15, quad = l >> 4;

    const float* sq = scale + (size_t)b * CDIM;
    const float* zq = shift + (size_t)b * CDIM;
    const float* sk = scale + (size_t)(NB + b) * CDIM;
    const float* zk = shift + (size_t)(NB + b) * CDIM;

    // build normalized K window in LDS
    {
        int oct = tid & 31;
        int j00 = tid >> 5;
        float skv[8], zkv[8];
#pragma unroll
        for (int e = 0; e < 8; ++e) { skv[e] = sk[oct * 8 + e]; zkv[e] = zk[oct * 8 + e]; }
#pragma unroll
        for (int it = 0; it < 8; ++it) {
            int j = j00 + it * 8;
            int pix = (wh * 8 + (j >> 3)) * HH + ww * 8 + (j & 7);
            short8 kv = *(const short8*)(kt + ((size_t)b * NPIX + pix) * CDIM + oct * 8);
            short8 nv;
#pragma unroll
            for (int e = 0; e < 8; ++e) nv[e] = f2bf(bf2f(kv[e]) * skv[e] + zkv[e]);
            *(short8*)(&Ks[j * 264 + oct * 8]) = nv;
        }
    }
    __syncthreads();

    // S = Qn @ Kn^T / 16 ; wave w computes rows [16w,16w+16)
    {
        fx4 accS[4];
#pragma unroll
        for (int nt = 0; nt < 4; ++nt) { accS[nt][0]=0.f; accS[nt][1]=0.f; accS[nt][2]=0.f; accS[nt][3]=0.f; }
        int qi = 16 * w + lr;
        int pixq = (wh * 8 + (qi >> 3)) * HH + ww * 8 + (qi & 7);
        const short* qrow = qt + ((size_t)b * NPIX + pixq) * CDIM;
#pragma unroll
        for (int kc = 0; kc < 8; ++kc) {
            int c0 = kc * 32 + quad * 8;
            short8 qv = *(const short8*)(qrow + c0);
            short8 aq;
#pragma unroll
            for (int e = 0; e < 8; ++e) aq[e] = f2bf(bf2f(qv[e]) * sq[c0 + e] + zq[c0 + e]);
#pragma unroll
            for (int nt = 0; nt < 4; ++nt) {
                short8 bk8 = *(const short8*)(&Ks[(nt * 16 + lr) * 264 + c0]);
                accS[nt] = __builtin_amdgcn_mfma_f32_16x16x32_bf16(aq, bk8, accS[nt], 0, 0, 0);
            }
        }
#pragma unroll
        for (int nt = 0; nt < 4; ++nt)
#pragma unroll
            for (int r = 0; r < 4; ++r)
                SsF[(16 * w + quad * 4 + r) * 68 + nt * 16 + lr] = accS[nt][r] * 0.0625f;
    }
    __syncthreads();

    // softmax over rows (4 threads per row)
    {
        int row = tid >> 2, seg = tid & 3;
        float v[16];
#pragma unroll
        for (int k4 = 0; k4 < 4; ++k4) {
            fx4 t4 = *(const fx4*)(&SsF[row * 68 + seg * 16 + k4 * 4]);
            v[k4*4+0] = t4[0]; v[k4*4+1] = t4[1]; v[k4*4+2] = t4[2]; v[k4*4+3] = t4[3];
        }
        float m = v[0];
#pragma unroll
        for (int e = 1; e < 16; ++e) m = fmaxf(m, v[e]);
        m = fmaxf(m, __shfl_xor(m, 1));
        m = fmaxf(m, __shfl_xor(m, 2));
        float s = 0.f;
#pragma unroll
        for (int e = 0; e < 16; ++e) { v[e] = __expf(v[e] - m); s += v[e]; }
        s += __shfl_xor(s, 1);
        s += __shfl_xor(s, 2);
        float inv = 1.0f / s;
        short8 p0, p1;
#pragma unroll
        for (int e = 0; e < 8; ++e) { p0[e] = f2bf(v[e] * inv); p1[e] = f2bf(v[8 + e] * inv); }
        *(short8*)(&Ps[row * 72 + seg * 16]) = p0;
        *(short8*)(&Ps[row * 72 + seg * 16 + 8]) = p1;
    }
    __syncthreads();

    // O = P @ Kn ; wave w computes channels [64w, 64w+64)
    fx4 accO[4][4];
#pragma unroll
    for (int mt = 0; mt < 4; ++mt)
#pragma unroll
        for (int nt = 0; nt < 4; ++nt) { accO[mt][nt][0]=0.f; accO[mt][nt][1]=0.f; accO[mt][nt][2]=0.f; accO[mt][nt][3]=0.f; }
#pragma unroll
    for (int kc2 = 0; kc2 < 2; ++kc2) {
        int j0 = kc2 * 32 + quad * 8;
        short8 ap[4];
#pragma unroll
        for (int mt = 0; mt < 4; ++mt)
            ap[mt] = *(const short8*)(&Ps[(mt * 16 + lr) * 72 + j0]);
#pragma unroll
        for (int nt = 0; nt < 4; ++nt) {
            int c = 64 * w + nt * 16 + lr;
            short8 bk8;
#pragma unroll
            for (int jj = 0; jj < 8; ++jj) bk8[jj] = Ks[(j0 + jj) * 264 + c];
#pragma unroll
            for (int mt = 0; mt < 4; ++mt)
                accO[mt][nt] = __builtin_amdgcn_mfma_f32_16x16x32_bf16(ap[mt], bk8, accO[mt][nt], 0, 0, 0);
        }
    }

    // epilogue in two halves (Os overlays Ss region), transposed, fp32 residual + store
    int half = w >> 1;
#pragma unroll
    for (int h2 = 0; h2 < 2; ++h2) {
        __syncthreads();
        if (half == h2) {
#pragma unroll
            for (int mt = 0; mt < 4; ++mt)
#pragma unroll
                for (int nt = 0; nt < 4; ++nt) {
                    int i = mt * 16 + quad * 4;
                    int cl = 64 * w + nt * 16 + lr - 128 * h2;   // 0..127
#pragma unroll
                    for (int r = 0; r < 4; ++r)
                        Os[(i + r) * 136 + cl] = f2bf(accO[mt][nt][r]);
                }
        }
        __syncthreads();
#pragma unroll
        for (int it = 0; it < 4; ++it) {
            int id = tid + it * 256;
            int cl = id & 127, h = id >> 7;   // h 0..7
            int cg = cl + 128 * h2;
            size_t gidx = ((size_t)(b * CDIM + cg)) * NPIX + (size_t)(wh * 8 + h) * HH + ww * 8;
            fx4 x0 = *(const fx4*)(xlo + gidx);
            fx4 x1 = *(const fx4*)(xlo + gidx + 4);
            fx4 r0, r1;
#pragma unroll
            for (int jj = 0; jj < 4; ++jj) {
                r0[jj] = bf2f(Os[(h * 8 + jj)     * 136 + cl]) + x0[jj];
                r1[jj] = bf2f(Os[(h * 8 + 4 + jj) * 136 + cl]) + x1[jj];
            }
            *(fx4*)(outp + gidx)     = r0;
            *(fx4*)(outp + gidx + 4) = r1;
        }
    }
}

extern "C" void kernel_launch(void* const* d_in, const int* in_sizes, int n_in,
                              void* d_out, int out_size, void* d_ws, size_t ws_size,
                              hipStream_t stream) {
    const float* xlo = (const float*)d_in[0];
    const float* xhi = (const float*)d_in[1];
    const float* wqp = (const float*)d_in[2];
    const float* wkp = (const float*)d_in[3];
    const float* gq  = (const float*)d_in[4];
    const float* bq  = (const float*)d_in[5];
    const float* gk  = (const float*)d_in[6];
    const float* bk  = (const float*)d_in[7];
    float* outp = (float*)d_out;
    char* ws = (char*)d_ws;
    size_t SZB = (size_t)NB * NPIX * CDIM * 2;   // 64 MB per bf16 tensor
    short* qt    = (short*)(ws);
    short* kt    = (short*)(ws + SZB);
    float* stats = (float*)(ws + 2 * SZB);
    float* scale = (float*)(ws + 2 * SZB + 4096);
    float* shift = (float*)(ws + 2 * SZB + 4096 + 16384);
    short* WB    = (short*)(ws + 2 * SZB + 4096 + 32768);
    fx2*   partials = (fx2*)(ws + 2 * SZB + 4096 + 32768 + 262144);  // 1 MB

    kW<<<dim3(8, 2), dim3(256), 0, stream>>>(wqp, wkp, WB);
    kG<<<dim3(256, 16), dim3(256), 0, stream>>>(xlo, xhi, WB, qt, kt, partials);
    kR<<<dim3(16), dim3(256), 0, stream>>>(partials, stats);
    kS<<<dim3(16), dim3(256), 0, stream>>>(stats, gq, bq, gk, bk, scale, shift);
    kA<<<dim3(2048), dim3(256), 0, stream>>>(qt, kt, scale, shift, xlo, outp);
}

// Round 4
// 500.477 us; speedup vs baseline: 4.7343x; 1.1191x over previous
//
#include <hip/hip_runtime.h>
#include <hip/hip_bf16.h>

using short8  = __attribute__((ext_vector_type(8))) short;
using short4v = __attribute__((ext_vector_type(4))) short;
using fx4     = __attribute__((ext_vector_type(4))) float;
using fx2     = __attribute__((ext_vector_type(2))) float;

#define NB 8
#define CDIM 256
#define HH 128
#define NPIX 16384
#define NG_ELEMS 131072.0f

#define XS_STRIDE 66   // 64 pix + 2 pad floats: 264B rows, 2-lane/bank LDS reads (free)

__device__ __forceinline__ float bf2f(short s) {
    union { unsigned u; float f; } c; c.u = ((unsigned)(unsigned short)s) << 16; return c.f;
}
__device__ __forceinline__ short f2bf(float f) {
    union { float f; unsigned u; } c; c.f = f;
    unsigned u = c.u;
    u += 0x7FFFu + ((u >> 16) & 1u);
    return (short)(u >> 16);
}
// packed RTNE fp32x2 -> bf16x2 (v_cvt_pk_bf16_f32 on gfx950)
__device__ __forceinline__ short2 f2bf2(float a, float b) {
    __hip_bfloat162 h = __float22bfloat162_rn(make_float2(a, b));
    union { __hip_bfloat162 b; short2 s; } c; c.b = h; return c.s;
}

// ---------------- Kernel W: wq/wk fp32 -> bf16 in MFMA fragment order ----------------
// WB[t][kc(8)][ntile(16)][lane(64)][8el]; lane=(quad*16+lr): value W[ntile*16+lr][kc*32+quad*8+e]
__global__ __launch_bounds__(256) void kW(const float* __restrict__ wq,
                                          const float* __restrict__ wk,
                                          short* __restrict__ WB) {
    int kc = blockIdx.x;      // 0..7
    int t  = blockIdx.y;      // 0..1
    const float* W = t ? wk : wq;
    int tid = threadIdx.x;
    int ntile = tid >> 4, lr = tid & 15;
    int n = ntile * 16 + lr;
#pragma unroll
    for (int quad = 0; quad < 4; ++quad) {
        const float* p = W + (size_t)n * CDIM + kc * 32 + quad * 8;
        fx4 v0 = *(const fx4*)p;
        fx4 v1 = *(const fx4*)(p + 4);
        union { short8 v; short2 h[4]; } s;
        s.h[0] = f2bf2(v0[0], v0[1]);
        s.h[1] = f2bf2(v0[2], v0[3]);
        s.h[2] = f2bf2(v1[0], v1[1]);
        s.h[3] = f2bf2(v1[2], v1[3]);
        *(short8*)(WB + ((((size_t)t * 8 + kc) * 16 + ntile) * 64 + quad * 16 + lr) * 8) = s.v;
    }
}

// ---------------- Kernel G: LDS-staged streaming GEMM + group partials -----------------
// global_load_lds staging, one barrier, A=W frags (L2-hot), B=X from LDS; group stats
// via per-block non-atomic partials.
__global__ __launch_bounds__(256, 2) void kG(const float* __restrict__ xlo,
                                             const float* __restrict__ xhi,
                                             const short* __restrict__ WB,
                                             short* __restrict__ qt,
                                             short* __restrict__ kt,
                                             fx2* __restrict__ partials) {
    __shared__ float Xs[256 * XS_STRIDE];      // 67.6 KB -> 2 blocks/CU

    int m0 = blockIdx.x * 64;                  // 64 pixels per block
    int zy = blockIdx.y;                       // 0..15
    int b = zy >> 1, t = zy & 1;
    const float* X = (t ? xhi : xlo) + (size_t)b * CDIM * NPIX;
    const short* WBt = WB + (size_t)t * 8 * 16 * 64 * 8;
    short* OUT = (t ? kt : qt) + (size_t)b * NPIX * CDIM;
    int tid = threadIdx.x;
    int w = tid >> 6, l = tid & 63, lr = l & 15, quad = l >> 4;

    // ---- stage: wave w DMAs channels [w*64, w*64+64) ; lane l -> pixel l -------------
    {
        int cbase = w * 64;
#pragma unroll
        for (int cc = 0; cc < 64; ++cc) {
            int c = cbase + cc;
            __builtin_amdgcn_global_load_lds(
                (const __attribute__((address_space(1))) void*)(X + (size_t)c * NPIX + m0 + l),
                (__attribute__((address_space(3))) void*)(&Xs[c * XS_STRIDE]),
                4, 0, 0);
        }
    }
    __syncthreads();

    fx4 acc[4][4];                             // [out-tile m][pix-tile nt]
#pragma unroll
    for (int m = 0; m < 4; ++m)
#pragma unroll
        for (int n = 0; n < 4; ++n) { acc[m][n][0]=0.f; acc[m][n][1]=0.f; acc[m][n][2]=0.f; acc[m][n][3]=0.f; }

    // ---- main loop: 8 kc steps, all data on-chip ------------------------------------
#pragma unroll
    for (int kc = 0; kc < 8; ++kc) {
        short8 af[4];
        const short* wb = WBt + (((size_t)kc * 16 + w * 4) * 64 + l) * 8;
#pragma unroll
        for (int m = 0; m < 4; ++m)
            af[m] = *(const short8*)(wb + (size_t)m * 64 * 8);

        const float* xq = &Xs[(kc * 32 + quad * 8) * XS_STRIDE + lr];
#pragma unroll
        for (int nt = 0; nt < 4; ++nt) {
            union { short8 v; short2 h[4]; } s;
#pragma unroll
            for (int j = 0; j < 4; ++j) {
                float a = xq[(2 * j    ) * XS_STRIDE + nt * 16];
                float bv = xq[(2 * j + 1) * XS_STRIDE + nt * 16];
                s.h[j] = f2bf2(a, bv);
            }
            short8 bf = s.v;
#pragma unroll
            for (int m = 0; m < 4; ++m)
                acc[m][nt] = __builtin_amdgcn_mfma_f32_16x16x32_bf16(af[m], bf, acc[m][nt], 0, 0, 0);
        }
    }

    // ---- group partials: lane owns o = w*64 + m*16 + quad*4 + r at pixel nt*16+lr ----
    {
        float gs[4], gss[4];
#pragma unroll
        for (int m = 0; m < 4; ++m) {
            gs[m] = 0.f; gss[m] = 0.f;
#pragma unroll
            for (int r = 0; r < 4; ++r) {
                float a0 = acc[m][0][r], a1 = acc[m][1][r], a2 = acc[m][2][r], a3 = acc[m][3][r];
                float sv = (a0 + a1) + (a2 + a3);
                float sq = (a0 * a0 + a1 * a1) + (a2 * a2 + a3 * a3);
                sv += __shfl_xor(sv, 1);  sq += __shfl_xor(sq, 1);
                sv += __shfl_xor(sv, 2);  sq += __shfl_xor(sq, 2);
                sv += __shfl_xor(sv, 4);  sq += __shfl_xor(sq, 4);
                sv += __shfl_xor(sv, 8);  sq += __shfl_xor(sq, 8);
                sv += __shfl_xor(sv, 16); sq += __shfl_xor(sq, 16);   // quad-pair combine
                gs[m] += sv; gss[m] += sq;
            }
        }
        if (l == 0 || l == 32) {
            int h = l >> 5;
            fx2* pp = partials + ((size_t)zy * 256 + blockIdx.x) * 32 + w * 8 + h;
#pragma unroll
            for (int m = 0; m < 4; ++m) {
                fx2 v; v[0] = gs[m]; v[1] = gss[m];
                pp[m * 2] = v;
            }
        }
    }

    // store bf16 [pix][o]: 8-byte short4 per (m,nt)
#pragma unroll
    for (int n = 0; n < 4; ++n) {
        int pix = m0 + n * 16 + lr;
        short* op = OUT + (size_t)pix * CDIM + w * 64 + quad * 4;
#pragma unroll
        for (int m = 0; m < 4; ++m) {
            short2 p0 = f2bf2(acc[m][n][0], acc[m][n][1]);
            short2 p1 = f2bf2(acc[m][n][2], acc[m][n][3]);
            short4v v; v[0] = p0.x; v[1] = p0.y; v[2] = p1.x; v[3] = p1.y;
            *(short4v*)(op + m * 16) = v;
        }
    }
}

// ---------------- Kernel R: reduce per-block partials -> stats -------------------------
__global__ __launch_bounds__(256) void kR(const fx2* __restrict__ partials,
                                          float* __restrict__ stats) {
    __shared__ fx2 red[8][32];
    int zy = blockIdx.x;                 // 0..15
    int b = zy >> 1, t = zy & 1;
    int tid = threadIdx.x;
    int j = tid >> 5, slot = tid & 31;
    fx2 acc; acc[0] = 0.f; acc[1] = 0.f;
#pragma unroll
    for (int i = 0; i < 32; ++i) {
        fx2 v = partials[((size_t)zy * 256 + j * 32 + i) * 32 + slot];
        acc[0] += v[0]; acc[1] += v[1];
    }
    red[j][slot] = acc;
    __syncthreads();
    if (tid < 32) {
        fx2 s = red[0][tid];
#pragma unroll
        for (int jj = 1; jj < 8; ++jj) { s[0] += red[jj][tid][0]; s[1] += red[jj][tid][1]; }
        float* st = stats + ((size_t)(t * NB + b) * 32 + tid) * 2;
        st[0] = s[0];
        st[1] = s[1];
    }
}

// ---------------- Kernel S: stats -> per-(tensor,b,o) scale/shift ----------------------
__global__ __launch_bounds__(256) void kS(const float* __restrict__ stats,
                                          const float* __restrict__ gq,
                                          const float* __restrict__ bq,
                                          const float* __restrict__ gk,
                                          const float* __restrict__ bk,
                                          float* __restrict__ scale,
                                          float* __restrict__ shift) {
    int id = blockIdx.x * 256 + threadIdx.x;   // 0..4095
    int t = id >> 11, b = (id >> 8) & 7, o = id & 255;
    int g = o >> 3;
    const float* st = stats + ((size_t)(t * NB + b) * 32 + g) * 2;
    float mean = st[0] * (1.0f / NG_ELEMS);
    float var  = st[1] * (1.0f / NG_ELEMS) - mean * mean;
    float rstd = rsqrtf(var + 1e-5f);
    float gamma = (t ? gk : gq)[o];
    float beta  = (t ? bk : bq)[o];
    float sc = gamma * rstd;
    scale[id] = sc;
    shift[id] = beta - mean * sc;
}

// ---------------- Kernel A: windowed attention + fp32 residual/output ------------------
// v2: in-register softmax (no score LDS buffer) -> 43 KB LDS = 3 blocks/CU; 4 barriers
// (was 7); one-pass epilogue with Os overlaying Ks; XCD-swizzled block order so
// ww-adjacent windows share L2 lines of xlo/outp.
__global__ __launch_bounds__(256, 3) void kA(const short* __restrict__ qt,
                                             const short* __restrict__ kt,
                                             const float* __restrict__ scale,
                                             const float* __restrict__ shift,
                                             const float* __restrict__ xlo,
                                             float* __restrict__ outp) {
    __shared__ short Ks[64 * 264];     // normalized K window [j][c], pad 8; reused as Os
    __shared__ short Ps[64 * 72];      // softmax probs bf16 [i][j], pad 8
    short* Os = &Ks[0];                // O bf16 [i(64)][c(256)], stride 264 (overlay)

    int bid = blockIdx.x;              // 0..2047
    int blk = ((bid & 7) << 8) | (bid >> 3);   // 8 XCDs x 256-block contiguous chunks
    int b = blk >> 8, wh = (blk >> 4) & 15, ww = blk & 15;
    int tid = threadIdx.x;
    int w = tid >> 6, l = tid & 63, lr = l & 15, quad = l >> 4;

    const float* sq = scale + (size_t)b * CDIM;
    const float* zq = shift + (size_t)b * CDIM;
    const float* sk = scale + (size_t)(NB + b) * CDIM;
    const float* zk = shift + (size_t)(NB + b) * CDIM;

    // build normalized K window in LDS
    {
        int oct = tid & 31;
        int j00 = tid >> 5;
        float skv[8], zkv[8];
#pragma unroll
        for (int e = 0; e < 8; ++e) { skv[e] = sk[oct * 8 + e]; zkv[e] = zk[oct * 8 + e]; }
#pragma unroll
        for (int it = 0; it < 8; ++it) {
            int j = j00 + it * 8;
            int pix = (wh * 8 + (j >> 3)) * HH + ww * 8 + (j & 7);
            short8 kv = *(const short8*)(kt + ((size_t)b * NPIX + pix) * CDIM + oct * 8);
            short8 nv;
#pragma unroll
            for (int e = 0; e < 8; ++e) nv[e] = f2bf(bf2f(kv[e]) * skv[e] + zkv[e]);
            *(short8*)(&Ks[j * 264 + oct * 8]) = nv;
        }
    }
    __syncthreads();

    // S = Qn @ Kn^T / 16 ; wave w computes rows [16w,16w+16); softmax fully in-register
    {
        fx4 accS[4];
#pragma unroll
        for (int nt = 0; nt < 4; ++nt) { accS[nt][0]=0.f; accS[nt][1]=0.f; accS[nt][2]=0.f; accS[nt][3]=0.f; }
        int qi = 16 * w + lr;
        int pixq = (wh * 8 + (qi >> 3)) * HH + ww * 8 + (qi & 7);
        const short* qrow = qt + ((size_t)b * NPIX + pixq) * CDIM;
#pragma unroll
        for (int kc = 0; kc < 8; ++kc) {
            int c0 = kc * 32 + quad * 8;
            short8 qv = *(const short8*)(qrow + c0);
            short8 aq;
#pragma unroll
            for (int e = 0; e < 8; ++e) aq[e] = f2bf(bf2f(qv[e]) * sq[c0 + e] + zq[c0 + e]);
#pragma unroll
            for (int nt = 0; nt < 4; ++nt) {
                short8 bk8 = *(const short8*)(&Ks[(nt * 16 + lr) * 264 + c0]);
                accS[nt] = __builtin_amdgcn_mfma_f32_16x16x32_bf16(aq, bk8, accS[nt], 0, 0, 0);
            }
        }
        // lane holds S[row=16w+quad*4+r][col=nt*16+lr]; row-reduce = in-lane over nt +
        // shfl_xor over lr bits (stays within the 16-lane group sharing the row).
#pragma unroll
        for (int r = 0; r < 4; ++r) {
            float v0 = accS[0][r] * 0.0625f, v1 = accS[1][r] * 0.0625f;
            float v2 = accS[2][r] * 0.0625f, v3 = accS[3][r] * 0.0625f;
            float m = fmaxf(fmaxf(v0, v1), fmaxf(v2, v3));
            m = fmaxf(m, __shfl_xor(m, 1));
            m = fmaxf(m, __shfl_xor(m, 2));
            m = fmaxf(m, __shfl_xor(m, 4));
            m = fmaxf(m, __shfl_xor(m, 8));
            float p0 = __expf(v0 - m), p1 = __expf(v1 - m);
            float p2 = __expf(v2 - m), p3 = __expf(v3 - m);
            float s = (p0 + p1) + (p2 + p3);
            s += __shfl_xor(s, 1);
            s += __shfl_xor(s, 2);
            s += __shfl_xor(s, 4);
            s += __shfl_xor(s, 8);
            float inv = 1.0f / s;
            int row = 16 * w + quad * 4 + r;
            Ps[row * 72 +  0 + lr] = f2bf(p0 * inv);
            Ps[row * 72 + 16 + lr] = f2bf(p1 * inv);
            Ps[row * 72 + 32 + lr] = f2bf(p2 * inv);
            Ps[row * 72 + 48 + lr] = f2bf(p3 * inv);
        }
    }
    __syncthreads();

    // O = P @ Kn ; wave w computes channels [64w, 64w+64)
    fx4 accO[4][4];
#pragma unroll
    for (int mt = 0; mt < 4; ++mt)
#pragma unroll
        for (int nt = 0; nt < 4; ++nt) { accO[mt][nt][0]=0.f; accO[mt][nt][1]=0.f; accO[mt][nt][2]=0.f; accO[mt][nt][3]=0.f; }
#pragma unroll
    for (int kc2 = 0; kc2 < 2; ++kc2) {
        int j0 = kc2 * 32 + quad * 8;
        short8 ap[4];
#pragma unroll
        for (int mt = 0; mt < 4; ++mt)
            ap[mt] = *(const short8*)(&Ps[(mt * 16 + lr) * 72 + j0]);
#pragma unroll
        for (int nt = 0; nt < 4; ++nt) {
            int c = 64 * w + nt * 16 + lr;
            short8 bk8;
#pragma unroll
            for (int jj = 0; jj < 8; ++jj) bk8[jj] = Ks[(j0 + jj) * 264 + c];
#pragma unroll
            for (int mt = 0; mt < 4; ++mt)
                accO[mt][nt] = __builtin_amdgcn_mfma_f32_16x16x32_bf16(ap[mt], bk8, accO[mt][nt], 0, 0, 0);
        }
    }

    __syncthreads();                   // Ks dead -> overlay Os
    // write full O (bf16) transposed into LDS: Os[i][c], stride 264
#pragma unroll
    for (int mt = 0; mt < 4; ++mt)
#pragma unroll
        for (int nt = 0; nt < 4; ++nt) {
            int i = mt * 16 + quad * 4;
            int c = 64 * w + nt * 16 + lr;
#pragma unroll
            for (int r = 0; r < 4; ++r)
                Os[(i + r) * 264 + c] = f2bf(accO[mt][nt][r]);
        }
    __syncthreads();

    // one-pass epilogue: thread tid owns channel cl=tid; 8 rows of 8 px (32 B) each
    {
        int cl = tid;
        const float* xrow = xlo + ((size_t)(b * CDIM + cl)) * NPIX + (size_t)(wh * 8) * HH + ww * 8;
        float* orow = outp + ((size_t)(b * CDIM + cl)) * NPIX + (size_t)(wh * 8) * HH + ww * 8;
#pragma unroll
        for (int h = 0; h < 8; ++h) {
            fx4 x0 = *(const fx4*)(xrow + (size_t)h * HH);
            fx4 x1 = *(const fx4*)(xrow + (size_t)h * HH + 4);
            fx4 r0, r1;
#pragma unroll
            for (int jj = 0; jj < 4; ++jj) {
                r0[jj] = bf2f(Os[(h * 8 + jj)     * 264 + cl]) + x0[jj];
                r1[jj] = bf2f(Os[(h * 8 + 4 + jj) * 264 + cl]) + x1[jj];
            }
            *(fx4*)(orow + (size_t)h * HH)     = r0;
            *(fx4*)(orow + (size_t)h * HH + 4) = r1;
        }
    }
}

extern "C" void kernel_launch(void* const* d_in, const int* in_sizes, int n_in,
                              void* d_out, int out_size, void* d_ws, size_t ws_size,
                              hipStream_t stream) {
    const float* xlo = (const float*)d_in[0];
    const float* xhi = (const float*)d_in[1];
    const float* wqp = (const float*)d_in[2];
    const float* wkp = (const float*)d_in[3];
    const float* gq  = (const float*)d_in[4];
    const float* bq  = (const float*)d_in[5];
    const float* gk  = (const float*)d_in[6];
    const float* bk  = (const float*)d_in[7];
    float* outp = (float*)d_out;
    char* ws = (char*)d_ws;
    size_t SZB = (size_t)NB * NPIX * CDIM * 2;   // 64 MB per bf16 tensor
    short* qt    = (short*)(ws);
    short* kt    = (short*)(ws + SZB);
    float* stats = (float*)(ws + 2 * SZB);
    float* scale = (float*)(ws + 2 * SZB + 4096);
    float* shift = (float*)(ws + 2 * SZB + 4096 + 16384);
    short* WB    = (short*)(ws + 2 * SZB + 4096 + 32768);
    fx2*   partials = (fx2*)(ws + 2 * SZB + 4096 + 32768 + 262144);  // 1 MB

    kW<<<dim3(8, 2), dim3(256), 0, stream>>>(wqp, wkp, WB);
    kG<<<dim3(256, 16), dim3(256), 0, stream>>>(xlo, xhi, WB, qt, kt, partials);
    kR<<<dim3(16), dim3(256), 0, stream>>>(partials, stats);
    kS<<<dim3(16), dim3(256), 0, stream>>>(stats, gq, bq, gk, bk, scale, shift);
    kA<<<dim3(2048), dim3(256), 0, stream>>>(qt, kt, scale, shift, xlo, outp);
}